// Round 1
// baseline (10691.299 us; speedup 1.0000x reference)
//
#include <hip/hip_runtime.h>
#include <hip/hip_bf16.h>

// LightGCNLiteUser: 3x SpMM(uu) accumulate, combine, filtered SpMM(g) to items,
// batched dot. All f32. COO scatter-atomic formulation, 16 lanes per edge.

#define THREADS 256

__global__ __launch_bounds__(THREADS) void spmm_atomic_kernel(
    const int* __restrict__ rows, const int* __restrict__ cols,
    const float* __restrict__ vals, const float* __restrict__ x,
    float* __restrict__ y, int nnz)
{
    long long gid = (long long)blockIdx.x * THREADS + threadIdx.x;
    int e = (int)(gid >> 4);
    if (e >= nnz) return;
    int part = (int)(gid & 15);
    int r = rows[e];
    int c = cols[e];
    float v = vals[e];
    float4 xv = reinterpret_cast<const float4*>(x)[(long long)c * 16 + part];
    float* yp = y + (long long)r * 64 + part * 4;
    atomicAdd(yp + 0, v * xv.x);
    atomicAdd(yp + 1, v * xv.y);
    atomicAdd(yp + 2, v * xv.z);
    atomicAdd(yp + 3, v * xv.w);
}

// g-graph SpMM, but only edges with row >= nU (item rows) and col < nU
// (user cols; item cols gather zeros) matter. Output indexed by (row - nU).
__global__ __launch_bounds__(THREADS) void spmm_g_items_kernel(
    const int* __restrict__ rows, const int* __restrict__ cols,
    const float* __restrict__ vals, const float* __restrict__ x,
    float* __restrict__ y_items, int nnz, int nU)
{
    long long gid = (long long)blockIdx.x * THREADS + threadIdx.x;
    int e = (int)(gid >> 4);
    if (e >= nnz) return;
    int r = rows[e];
    if (r < nU) return;
    int c = cols[e];
    if (c >= nU) return;
    int part = (int)(gid & 15);
    float v = vals[e];
    float4 xv = reinterpret_cast<const float4*>(x)[(long long)c * 16 + part];
    float* yp = y_items + (long long)(r - nU) * 64 + part * 4;
    atomicAdd(yp + 0, v * xv.x);
    atomicAdd(yp + 1, v * xv.y);
    atomicAdd(yp + 2, v * xv.z);
    atomicAdd(yp + 3, v * xv.w);
}

// all_users = (user_emb + e1 + e2 + e3) * 0.25, written into e1's buffer
// (same-index read/write, safe).
__global__ __launch_bounds__(THREADS) void combine_kernel(
    const float4* __restrict__ e0, float4* __restrict__ e1,
    const float4* __restrict__ e2, const float4* __restrict__ e3, int n4)
{
    int i = blockIdx.x * THREADS + threadIdx.x;
    if (i >= n4) return;
    float4 a = e0[i], b = e1[i], c = e2[i], d = e3[i];
    float4 o;
    o.x = 0.25f * (a.x + b.x + c.x + d.x);
    o.y = 0.25f * (a.y + b.y + c.y + d.y);
    o.z = 0.25f * (a.z + b.z + c.z + d.z);
    o.w = 0.25f * (a.w + b.w + c.w + d.w);
    e1[i] = o;
}

__global__ __launch_bounds__(THREADS) void final_dot_kernel(
    const float* __restrict__ au, const float* __restrict__ it,
    const int* __restrict__ users, const int* __restrict__ items,
    float* __restrict__ out, int B)
{
    int gid = blockIdx.x * THREADS + threadIdx.x;
    int b = gid >> 4;
    if (b >= B) return;
    int part = gid & 15;
    float4 uv = reinterpret_cast<const float4*>(au)[(long long)users[b] * 16 + part];
    float4 iv = reinterpret_cast<const float4*>(it)[(long long)items[b] * 16 + part];
    float s = uv.x * iv.x + uv.y * iv.y + uv.z * iv.z + uv.w * iv.w;
    // 16-lane group reduce (groups aligned to lane&15 since 16 | 64)
    s += __shfl_xor(s, 1);
    s += __shfl_xor(s, 2);
    s += __shfl_xor(s, 4);
    s += __shfl_xor(s, 8);
    if (part == 0) out[b] = s;
}

extern "C" void kernel_launch(void* const* d_in, const int* in_sizes, int n_in,
                              void* d_out, int out_size, void* d_ws, size_t ws_size,
                              hipStream_t stream) {
    const float* user_emb = (const float*)d_in[0];
    const int*   uu_rows  = (const int*)d_in[1];
    const int*   uu_cols  = (const int*)d_in[2];
    const float* uu_vals  = (const float*)d_in[3];
    const int*   g_rows   = (const int*)d_in[4];
    const int*   g_cols   = (const int*)d_in[5];
    const float* g_vals   = (const float*)d_in[6];
    const int*   users    = (const int*)d_in[7];
    const int*   items    = (const int*)d_in[8];

    const int U = in_sizes[0] / 64;        // 131072
    const int E_UU = in_sizes[1];          // 4000000
    const int E_G  = in_sizes[4];          // 4000000
    const int B    = in_sizes[7];          // 8192
    const int M    = 32768;                // num_items (python scalar on device; fixed)

    const size_t embBytes = (size_t)U * 64 * sizeof(float);   // 32 MB
    float* E1 = (float*)d_ws;                                  // layer-1 emb, later all_users
    float* E2 = (float*)((char*)d_ws + embBytes);
    float* E3 = (float*)((char*)d_ws + 2 * embBytes);
    float* IT = (float*)((char*)d_ws + 3 * embBytes);          // item accumulator, 8 MB

    const size_t itBytes = (size_t)M * 64 * sizeof(float);

    int spmmGrid = (int)(((long long)E_UU * 16 + THREADS - 1) / THREADS);
    int gGrid    = (int)(((long long)E_G  * 16 + THREADS - 1) / THREADS);

    // layer 1
    hipMemsetAsync(E1, 0, embBytes, stream);
    spmm_atomic_kernel<<<spmmGrid, THREADS, 0, stream>>>(uu_rows, uu_cols, uu_vals, user_emb, E1, E_UU);
    // layer 2
    hipMemsetAsync(E2, 0, embBytes, stream);
    spmm_atomic_kernel<<<spmmGrid, THREADS, 0, stream>>>(uu_rows, uu_cols, uu_vals, E1, E2, E_UU);
    // layer 3
    hipMemsetAsync(E3, 0, embBytes, stream);
    spmm_atomic_kernel<<<spmmGrid, THREADS, 0, stream>>>(uu_rows, uu_cols, uu_vals, E2, E3, E_UU);

    // all_users = (user_emb + E1 + E2 + E3)/4  -> into E1
    int n4 = U * 16;
    combine_kernel<<<(n4 + THREADS - 1) / THREADS, THREADS, 0, stream>>>(
        (const float4*)user_emb, (float4*)E1, (const float4*)E2, (const float4*)E3, n4);

    // item propagation (filtered g edges)
    hipMemsetAsync(IT, 0, itBytes, stream);
    spmm_g_items_kernel<<<gGrid, THREADS, 0, stream>>>(g_rows, g_cols, g_vals, E1, IT, E_G, U);

    // gamma
    final_dot_kernel<<<(B * 16 + THREADS - 1) / THREADS, THREADS, 0, stream>>>(
        E1, IT, users, items, (float*)d_out, B);
}

// Round 2
// 1713.426 us; speedup vs baseline: 6.2397x; 6.2397x over previous
//
#include <hip/hip_runtime.h>
#include <hip/hip_bf16.h>

#define THREADS 256

// ---------------------------------------------------------------------------
// CSR build: histogram -> exclusive scan -> scatter (packed int2 {col, val})
// ---------------------------------------------------------------------------

__global__ __launch_bounds__(THREADS) void hist_uu(
    const int* __restrict__ rows, int nnz, int* __restrict__ cnt)
{
    int stride = gridDim.x * THREADS;
    for (int e = blockIdx.x * THREADS + threadIdx.x; e < nnz; e += stride)
        atomicAdd(&cnt[rows[e]], 1);
}

__global__ __launch_bounds__(THREADS) void hist_g(
    const int* __restrict__ rows, const int* __restrict__ cols,
    int nnz, int* __restrict__ cnt, int nU)
{
    int stride = gridDim.x * THREADS;
    for (int e = blockIdx.x * THREADS + threadIdx.x; e < nnz; e += stride) {
        int r = rows[e];
        if (r >= nU && cols[e] < nU) atomicAdd(&cnt[r - nU], 1);
    }
}

// Each block sums a 512-entry chunk of cnt -> partial[block]
__global__ __launch_bounds__(THREADS) void scan_block_sums(
    const int* __restrict__ cnt, int* __restrict__ partial)
{
    __shared__ int lds[THREADS];
    int i = blockIdx.x * 512 + threadIdx.x * 2;
    lds[threadIdx.x] = cnt[i] + cnt[i + 1];
    __syncthreads();
    for (int off = 128; off > 0; off >>= 1) {
        if (threadIdx.x < off) lds[threadIdx.x] += lds[threadIdx.x + off];
        __syncthreads();
    }
    if (threadIdx.x == 0) partial[blockIdx.x] = lds[0];
}

// Serial exclusive scan of partials (nb <= 256, trivial); also writes rp[n]=total
__global__ void scan_partials(int* partial, int nb, int* rp, int n)
{
    if (threadIdx.x == 0 && blockIdx.x == 0) {
        int run = 0;
        for (int i = 0; i < nb; i++) { int v = partial[i]; partial[i] = run; run += v; }
        rp[n] = run;
    }
}

// Exclusive scan within each 512-chunk + chunk base -> rp
__global__ __launch_bounds__(THREADS) void scan_write(
    const int* __restrict__ cnt, const int* __restrict__ partial, int* __restrict__ rp)
{
    __shared__ int lds[THREADS];
    int t = threadIdx.x;
    int i = blockIdx.x * 512 + t * 2;
    int a0 = cnt[i], a1 = cnt[i + 1];
    int s = a0 + a1;
    lds[t] = s;
    __syncthreads();
    for (int off = 1; off < THREADS; off <<= 1) {
        int v = (t >= off) ? lds[t - off] : 0;
        __syncthreads();
        lds[t] += v;
        __syncthreads();
    }
    int excl = lds[t] - s;
    int base = partial[blockIdx.x];
    rp[i] = base + excl;
    rp[i + 1] = base + excl + a0;
}

__global__ __launch_bounds__(THREADS) void scatter_uu(
    const int* __restrict__ rows, const int* __restrict__ cols,
    const float* __restrict__ vals, int nnz, int* __restrict__ cur,
    int2* __restrict__ se)
{
    int stride = gridDim.x * THREADS;
    for (int e = blockIdx.x * THREADS + threadIdx.x; e < nnz; e += stride) {
        int p = atomicAdd(&cur[rows[e]], 1);
        se[p] = make_int2(cols[e], __float_as_int(vals[e]));
    }
}

__global__ __launch_bounds__(THREADS) void scatter_g(
    const int* __restrict__ rows, const int* __restrict__ cols,
    const float* __restrict__ vals, int nnz, int* __restrict__ cur,
    int2* __restrict__ se, int nU)
{
    int stride = gridDim.x * THREADS;
    for (int e = blockIdx.x * THREADS + threadIdx.x; e < nnz; e += stride) {
        int r = rows[e];
        if (r >= nU) {
            int c = cols[e];
            if (c < nU) {
                int p = atomicAdd(&cur[r - nU], 1);
                se[p] = make_int2(c, __float_as_int(vals[e]));
            }
        }
    }
}

// ---------------------------------------------------------------------------
// Gather SpMM: one wave per row, lane = feature. Optional acc += epilogue.
// ---------------------------------------------------------------------------
__global__ __launch_bounds__(THREADS) void spmm_csr(
    const int* __restrict__ rp, const int2* __restrict__ se,
    const float* __restrict__ x, float* __restrict__ y,
    float* __restrict__ acc, int nrows)
{
    int w = (blockIdx.x * THREADS + threadIdx.x) >> 6;
    int lane = threadIdx.x & 63;
    if (w >= nrows) return;
    int s = rp[w], e = rp[w + 1];
    float a = 0.f;
    for (int i = s; i < e; ++i) {
        int2 ev = se[i];                       // wave-uniform -> scalar load
        a += __int_as_float(ev.y) * x[(size_t)ev.x * 64 + lane];
    }
    if (y)   y[(size_t)w * 64 + lane] = a;
    if (acc) acc[(size_t)w * 64 + lane] += a;
}

// all_users = 0.25*(user_emb + ACC), written into ACC
__global__ __launch_bounds__(THREADS) void combine2(
    const float4* __restrict__ ue, float4* __restrict__ accau, int n4)
{
    int i = blockIdx.x * THREADS + threadIdx.x;
    if (i >= n4) return;
    float4 a = ue[i], b = accau[i];
    accau[i] = make_float4(0.25f * (a.x + b.x), 0.25f * (a.y + b.y),
                           0.25f * (a.z + b.z), 0.25f * (a.w + b.w));
}

__global__ __launch_bounds__(THREADS) void final_dot_kernel(
    const float* __restrict__ au, const float* __restrict__ it,
    const int* __restrict__ users, const int* __restrict__ items,
    float* __restrict__ out, int B)
{
    int gid = blockIdx.x * THREADS + threadIdx.x;
    int b = gid >> 4;
    if (b >= B) return;
    int part = gid & 15;
    float4 uv = reinterpret_cast<const float4*>(au)[(long long)users[b] * 16 + part];
    float4 iv = reinterpret_cast<const float4*>(it)[(long long)items[b] * 16 + part];
    float s = uv.x * iv.x + uv.y * iv.y + uv.z * iv.z + uv.w * iv.w;
    s += __shfl_xor(s, 1);
    s += __shfl_xor(s, 2);
    s += __shfl_xor(s, 4);
    s += __shfl_xor(s, 8);
    if (part == 0) out[b] = s;
}

// ---------------------------------------------------------------------------
// Fallback (R1 atomic path, 104 MB ws) in case ws_size < CSR-path needs
// ---------------------------------------------------------------------------
__global__ __launch_bounds__(THREADS) void spmm_atomic_kernel(
    const int* __restrict__ rows, const int* __restrict__ cols,
    const float* __restrict__ vals, const float* __restrict__ x,
    float* __restrict__ y, int nnz)
{
    long long gid = (long long)blockIdx.x * THREADS + threadIdx.x;
    int e = (int)(gid >> 4);
    if (e >= nnz) return;
    int part = (int)(gid & 15);
    int r = rows[e];
    int c = cols[e];
    float v = vals[e];
    float4 xv = reinterpret_cast<const float4*>(x)[(long long)c * 16 + part];
    float* yp = y + (long long)r * 64 + part * 4;
    atomicAdd(yp + 0, v * xv.x);
    atomicAdd(yp + 1, v * xv.y);
    atomicAdd(yp + 2, v * xv.z);
    atomicAdd(yp + 3, v * xv.w);
}

__global__ __launch_bounds__(THREADS) void spmm_g_items_kernel(
    const int* __restrict__ rows, const int* __restrict__ cols,
    const float* __restrict__ vals, const float* __restrict__ x,
    float* __restrict__ y_items, int nnz, int nU)
{
    long long gid = (long long)blockIdx.x * THREADS + threadIdx.x;
    int e = (int)(gid >> 4);
    if (e >= nnz) return;
    int r = rows[e];
    if (r < nU) return;
    int c = cols[e];
    if (c >= nU) return;
    int part = (int)(gid & 15);
    float v = vals[e];
    float4 xv = reinterpret_cast<const float4*>(x)[(long long)c * 16 + part];
    float* yp = y_items + (long long)(r - nU) * 64 + part * 4;
    atomicAdd(yp + 0, v * xv.x);
    atomicAdd(yp + 1, v * xv.y);
    atomicAdd(yp + 2, v * xv.z);
    atomicAdd(yp + 3, v * xv.w);
}

__global__ __launch_bounds__(THREADS) void combine_kernel(
    const float4* __restrict__ e0, float4* __restrict__ e1,
    const float4* __restrict__ e2, const float4* __restrict__ e3, int n4)
{
    int i = blockIdx.x * THREADS + threadIdx.x;
    if (i >= n4) return;
    float4 a = e0[i], b = e1[i], c = e2[i], d = e3[i];
    e1[i] = make_float4(0.25f * (a.x + b.x + c.x + d.x), 0.25f * (a.y + b.y + c.y + d.y),
                        0.25f * (a.z + b.z + c.z + d.z), 0.25f * (a.w + b.w + c.w + d.w));
}

// ---------------------------------------------------------------------------

extern "C" void kernel_launch(void* const* d_in, const int* in_sizes, int n_in,
                              void* d_out, int out_size, void* d_ws, size_t ws_size,
                              hipStream_t stream) {
    const float* user_emb = (const float*)d_in[0];
    const int*   uu_rows  = (const int*)d_in[1];
    const int*   uu_cols  = (const int*)d_in[2];
    const float* uu_vals  = (const float*)d_in[3];
    const int*   g_rows   = (const int*)d_in[4];
    const int*   g_cols   = (const int*)d_in[5];
    const float* g_vals   = (const float*)d_in[6];
    const int*   users    = (const int*)d_in[7];
    const int*   items    = (const int*)d_in[8];

    const int U    = in_sizes[0] / 64;     // 131072
    const int E_UU = in_sizes[1];          // 4000000
    const int E_G  = in_sizes[4];          // 4000000
    const int B    = in_sizes[7];          // 8192
    const int M    = 32768;                // num_items (fixed per reference)

    const size_t EMB = (size_t)U * 64 * sizeof(float);   // 32 MB
    const size_t MB  = 1024 * 1024;

    char* ws = (char*)d_ws;

    // CSR-path layout (~130 MB):
    float* ACC = (float*)(ws);                      // 0   .. 32M
    float* P0  = (float*)(ws + EMB);                // 32M .. 64M  (g-CSR overlay later)
    float* P1  = (float*)(ws + 2 * EMB);            // 64M .. 96M  (IT overlay later)
    // g overlay (valid after combine; P0/P1 dead then)
    int*  cnt_g = (int*)(ws + EMB);                                  // 32M
    int*  rp_g  = (int*)(ws + EMB + 512 * 1024);                     // 32.5M
    int*  cur_g = (int*)(ws + EMB + 1 * MB);                         // 33M
    int2* se_g  = (int2*)(ws + EMB + MB + 512 * 1024);               // 33.5M .. 65.5M
    float* IT   = (float*)(ws + EMB + 34 * MB);                      // 66M .. 74M
    // uu CSR region
    char* base3 = ws + 3 * EMB;                                      // 96M
    int*  cnt_u = (int*)(base3);                                     // 512K
    int*  cur_u = (int*)(base3 + 512 * 1024);                        // 512K
    int*  partial = (int*)(base3 + 1 * MB);                          // 16K
    int*  rp_u  = (int*)(base3 + 1 * MB + 16 * 1024);                // ~1M
    int2* se_u  = (int2*)(base3 + 2 * MB + 16 * 1024);               // 32 MB
    const size_t needCSR = 3 * EMB + 2 * MB + 16 * 1024 + (size_t)E_UU * 8 + 1024;

    int histGrid = 4096;
    int n4 = U * 16;

    if (ws_size >= needCSR) {
        // ---- build uu CSR ----
        hipMemsetAsync(cnt_u, 0, (size_t)U * 4, stream);
        hist_uu<<<histGrid, THREADS, 0, stream>>>(uu_rows, E_UU, cnt_u);
        scan_block_sums<<<U / 512, THREADS, 0, stream>>>(cnt_u, partial);
        scan_partials<<<1, 64, 0, stream>>>(partial, U / 512, rp_u, U);
        scan_write<<<U / 512, THREADS, 0, stream>>>(cnt_u, partial, rp_u);
        hipMemcpyAsync(cur_u, rp_u, (size_t)U * 4, hipMemcpyDeviceToDevice, stream);
        scatter_uu<<<histGrid, THREADS, 0, stream>>>(uu_rows, uu_cols, uu_vals, E_UU, cur_u, se_u);

        // ---- 3 layers, acc-folded ----
        hipMemsetAsync(ACC, 0, EMB, stream);
        spmm_csr<<<U / 4, THREADS, 0, stream>>>(rp_u, se_u, user_emb, P0, ACC, U);
        spmm_csr<<<U / 4, THREADS, 0, stream>>>(rp_u, se_u, P0, P1, ACC, U);
        spmm_csr<<<U / 4, THREADS, 0, stream>>>(rp_u, se_u, P1, (float*)nullptr, ACC, U);

        // all_users -> ACC
        combine2<<<(n4 + THREADS - 1) / THREADS, THREADS, 0, stream>>>(
            (const float4*)user_emb, (float4*)ACC, n4);

        // ---- build g (item-row) CSR, filtered ----
        hipMemsetAsync(cnt_g, 0, (size_t)M * 4, stream);
        hist_g<<<histGrid, THREADS, 0, stream>>>(g_rows, g_cols, E_G, cnt_g, U);
        scan_block_sums<<<M / 512, THREADS, 0, stream>>>(cnt_g, partial);
        scan_partials<<<1, 64, 0, stream>>>(partial, M / 512, rp_g, M);
        scan_write<<<M / 512, THREADS, 0, stream>>>(cnt_g, partial, rp_g);
        hipMemcpyAsync(cur_g, rp_g, (size_t)M * 4, hipMemcpyDeviceToDevice, stream);
        scatter_g<<<histGrid, THREADS, 0, stream>>>(g_rows, g_cols, g_vals, E_G, cur_g, se_g, U);

        // ---- item propagation + gamma ----
        spmm_csr<<<M / 4, THREADS, 0, stream>>>(rp_g, se_g, ACC, IT, (float*)nullptr, M);
        final_dot_kernel<<<(B * 16 + THREADS - 1) / THREADS, THREADS, 0, stream>>>(
            ACC, IT, users, items, (float*)d_out, B);
    } else {
        // ---- fallback: R1 atomic path (needs 104 MB) ----
        float* E1 = (float*)ws;
        float* E2 = (float*)(ws + EMB);
        float* E3 = (float*)(ws + 2 * EMB);
        float* IT2 = (float*)(ws + 3 * EMB);
        const size_t itBytes = (size_t)M * 64 * sizeof(float);
        int spmmGrid = (int)(((long long)E_UU * 16 + THREADS - 1) / THREADS);
        int gGrid    = (int)(((long long)E_G * 16 + THREADS - 1) / THREADS);

        hipMemsetAsync(E1, 0, EMB, stream);
        spmm_atomic_kernel<<<spmmGrid, THREADS, 0, stream>>>(uu_rows, uu_cols, uu_vals, user_emb, E1, E_UU);
        hipMemsetAsync(E2, 0, EMB, stream);
        spmm_atomic_kernel<<<spmmGrid, THREADS, 0, stream>>>(uu_rows, uu_cols, uu_vals, E1, E2, E_UU);
        hipMemsetAsync(E3, 0, EMB, stream);
        spmm_atomic_kernel<<<spmmGrid, THREADS, 0, stream>>>(uu_rows, uu_cols, uu_vals, E2, E3, E_UU);
        combine_kernel<<<(n4 + THREADS - 1) / THREADS, THREADS, 0, stream>>>(
            (const float4*)user_emb, (float4*)E1, (const float4*)E2, (const float4*)E3, n4);
        hipMemsetAsync(IT2, 0, itBytes, stream);
        spmm_g_items_kernel<<<gGrid, THREADS, 0, stream>>>(g_rows, g_cols, g_vals, E1, IT2, E_G, U);
        final_dot_kernel<<<(B * 16 + THREADS - 1) / THREADS, THREADS, 0, stream>>>(
            E1, IT2, users, items, (float*)d_out, B);
    }
}

// Round 6
// 1043.012 us; speedup vs baseline: 10.2504x; 1.6428x over previous
//
#include <hip/hip_runtime.h>
#include <hip/hip_bf16.h>

#define THREADS 256

// ---------------------------------------------------------------------------
// CSR build: histogram -> exclusive scan -> scatter (packed int2 {col, val})
// ---------------------------------------------------------------------------

__global__ __launch_bounds__(THREADS) void hist_uu(
    const int* __restrict__ rows, int nnz, int* __restrict__ cnt)
{
    int stride = gridDim.x * THREADS;
    for (int e = blockIdx.x * THREADS + threadIdx.x; e < nnz; e += stride)
        atomicAdd(&cnt[rows[e]], 1);
}

__global__ __launch_bounds__(THREADS) void hist_g(
    const int* __restrict__ rows, const int* __restrict__ cols,
    int nnz, int* __restrict__ cnt, int nU)
{
    int stride = gridDim.x * THREADS;
    for (int e = blockIdx.x * THREADS + threadIdx.x; e < nnz; e += stride) {
        int r = rows[e];
        if (r >= nU && cols[e] < nU) atomicAdd(&cnt[r - nU], 1);
    }
}

// Each block sums a 512-entry chunk of cnt -> partial[block]
__global__ __launch_bounds__(THREADS) void scan_block_sums(
    const int* __restrict__ cnt, int* __restrict__ partial)
{
    __shared__ int lds[THREADS];
    int i = blockIdx.x * 512 + threadIdx.x * 2;
    lds[threadIdx.x] = cnt[i] + cnt[i + 1];
    __syncthreads();
    for (int off = 128; off > 0; off >>= 1) {
        if (threadIdx.x < off) lds[threadIdx.x] += lds[threadIdx.x + off];
        __syncthreads();
    }
    if (threadIdx.x == 0) partial[blockIdx.x] = lds[0];
}

// Serial exclusive scan of partials (nb small); also writes rp[n]=total
__global__ void scan_partials(int* partial, int nb, int* rp, int n)
{
    if (threadIdx.x == 0 && blockIdx.x == 0) {
        int run = 0;
        for (int i = 0; i < nb; i++) { int v = partial[i]; partial[i] = run; run += v; }
        rp[n] = run;
    }
}

// Exclusive scan within each 512-chunk + chunk base -> rp
__global__ __launch_bounds__(THREADS) void scan_write(
    const int* __restrict__ cnt, const int* __restrict__ partial, int* __restrict__ rp)
{
    __shared__ int lds[THREADS];
    int t = threadIdx.x;
    int i = blockIdx.x * 512 + t * 2;
    int a0 = cnt[i], a1 = cnt[i + 1];
    int s = a0 + a1;
    lds[t] = s;
    __syncthreads();
    for (int off = 1; off < THREADS; off <<= 1) {
        int v = (t >= off) ? lds[t - off] : 0;
        __syncthreads();
        lds[t] += v;
        __syncthreads();
    }
    int excl = lds[t] - s;
    int base = partial[blockIdx.x];
    rp[i] = base + excl;
    rp[i + 1] = base + excl + a0;
}

__global__ __launch_bounds__(THREADS) void scatter_uu(
    const int* __restrict__ rows, const int* __restrict__ cols,
    const float* __restrict__ vals, int nnz, int* __restrict__ cur,
    int2* __restrict__ se)
{
    int stride = gridDim.x * THREADS;
    for (int e = blockIdx.x * THREADS + threadIdx.x; e < nnz; e += stride) {
        int p = atomicAdd(&cur[rows[e]], 1);
        se[p] = make_int2(cols[e], __float_as_int(vals[e]));
    }
}

__global__ __launch_bounds__(THREADS) void scatter_g(
    const int* __restrict__ rows, const int* __restrict__ cols,
    const float* __restrict__ vals, int nnz, int* __restrict__ cur,
    int2* __restrict__ se, int nU)
{
    int stride = gridDim.x * THREADS;
    for (int e = blockIdx.x * THREADS + threadIdx.x; e < nnz; e += stride) {
        int r = rows[e];
        if (r >= nU) {
            int c = cols[e];
            if (c < nU) {
                int p = atomicAdd(&cur[r - nU], 1);
                se[p] = make_int2(c, __float_as_int(vals[e]));
            }
        }
    }
}

// ---------------------------------------------------------------------------
// Gather SpMM v2: one wave per row, lane = feature.
// Cooperative edge fetch (one coalesced 512B read grabs up to 64 edges),
// readlane broadcast -> scalar-base gathers, unroll x8 with independent
// accumulators so 8 gathers stay in flight per wave.
// ---------------------------------------------------------------------------
__global__ __launch_bounds__(THREADS) void spmm_csr2(
    const int* __restrict__ rp, const long long* __restrict__ se,
    const float* __restrict__ x, float* __restrict__ y,
    float* __restrict__ acc, int nrows)
{
    int w = (blockIdx.x * THREADS + threadIdx.x) >> 6;
    int lane = threadIdx.x & 63;
    if (w >= nrows) return;
    int s = rp[w], e = rp[w + 1];

    float a0 = 0.f, a1 = 0.f, a2 = 0.f, a3 = 0.f;
    float a4 = 0.f, a5 = 0.f, a6 = 0.f, a7 = 0.f;

    for (int base = s; base < e; base += 64) {
        int avail = e - base;                       // > 0
        long long packed = 0;
        if (lane < avail)
            packed = __builtin_nontemporal_load(se + base + lane);
        int evc = (int)(packed & 0xffffffffLL);     // col (0 for pad lanes)
        int evv = (int)(packed >> 32);              // val bits (0.0f for pad)
        int n = avail < 64 ? avail : 64;
        int nIter = (n + 7) & ~7;                   // pad lanes contribute 0
        for (int i = 0; i < nIter; i += 8) {
            int   c0 = __builtin_amdgcn_readlane(evc, i + 0);
            float v0 = __int_as_float(__builtin_amdgcn_readlane(evv, i + 0));
            int   c1 = __builtin_amdgcn_readlane(evc, i + 1);
            float v1 = __int_as_float(__builtin_amdgcn_readlane(evv, i + 1));
            int   c2 = __builtin_amdgcn_readlane(evc, i + 2);
            float v2 = __int_as_float(__builtin_amdgcn_readlane(evv, i + 2));
            int   c3 = __builtin_amdgcn_readlane(evc, i + 3);
            float v3 = __int_as_float(__builtin_amdgcn_readlane(evv, i + 3));
            int   c4 = __builtin_amdgcn_readlane(evc, i + 4);
            float v4 = __int_as_float(__builtin_amdgcn_readlane(evv, i + 4));
            int   c5 = __builtin_amdgcn_readlane(evc, i + 5);
            float v5 = __int_as_float(__builtin_amdgcn_readlane(evv, i + 5));
            int   c6 = __builtin_amdgcn_readlane(evc, i + 6);
            float v6 = __int_as_float(__builtin_amdgcn_readlane(evv, i + 6));
            int   c7 = __builtin_amdgcn_readlane(evc, i + 7);
            float v7 = __int_as_float(__builtin_amdgcn_readlane(evv, i + 7));
            float g0 = x[((long long)c0 << 6) + lane];
            float g1 = x[((long long)c1 << 6) + lane];
            float g2 = x[((long long)c2 << 6) + lane];
            float g3 = x[((long long)c3 << 6) + lane];
            float g4 = x[((long long)c4 << 6) + lane];
            float g5 = x[((long long)c5 << 6) + lane];
            float g6 = x[((long long)c6 << 6) + lane];
            float g7 = x[((long long)c7 << 6) + lane];
            a0 += v0 * g0; a1 += v1 * g1; a2 += v2 * g2; a3 += v3 * g3;
            a4 += v4 * g4; a5 += v5 * g5; a6 += v6 * g6; a7 += v7 * g7;
        }
    }
    float a = ((a0 + a1) + (a2 + a3)) + ((a4 + a5) + (a6 + a7));
    long long oi = ((long long)w << 6) + lane;
    if (y)   __builtin_nontemporal_store(a, y + oi);
    if (acc) acc[oi] += a;
}

// all_users = 0.25*(user_emb + ACC), written into ACC
__global__ __launch_bounds__(THREADS) void combine2(
    const float4* __restrict__ ue, float4* __restrict__ accau, int n4)
{
    int i = blockIdx.x * THREADS + threadIdx.x;
    if (i >= n4) return;
    float4 a = ue[i], b = accau[i];
    accau[i] = make_float4(0.25f * (a.x + b.x), 0.25f * (a.y + b.y),
                           0.25f * (a.z + b.z), 0.25f * (a.w + b.w));
}

__global__ __launch_bounds__(THREADS) void final_dot_kernel(
    const float* __restrict__ au, const float* __restrict__ it,
    const int* __restrict__ users, const int* __restrict__ items,
    float* __restrict__ out, int B)
{
    int gid = blockIdx.x * THREADS + threadIdx.x;
    int b = gid >> 4;
    if (b >= B) return;
    int part = gid & 15;
    float4 uv = reinterpret_cast<const float4*>(au)[(long long)users[b] * 16 + part];
    float4 iv = reinterpret_cast<const float4*>(it)[(long long)items[b] * 16 + part];
    float s = uv.x * iv.x + uv.y * iv.y + uv.z * iv.z + uv.w * iv.w;
    s += __shfl_xor(s, 1);
    s += __shfl_xor(s, 2);
    s += __shfl_xor(s, 4);
    s += __shfl_xor(s, 8);
    if (part == 0) out[b] = s;
}

// ---------------------------------------------------------------------------
// Fallback (atomic path) in case ws_size < CSR-path needs
// ---------------------------------------------------------------------------
__global__ __launch_bounds__(THREADS) void spmm_atomic_kernel(
    const int* __restrict__ rows, const int* __restrict__ cols,
    const float* __restrict__ vals, const float* __restrict__ x,
    float* __restrict__ y, int nnz)
{
    long long gid = (long long)blockIdx.x * THREADS + threadIdx.x;
    int e = (int)(gid >> 4);
    if (e >= nnz) return;
    int part = (int)(gid & 15);
    int r = rows[e];
    int c = cols[e];
    float v = vals[e];
    float4 xv = reinterpret_cast<const float4*>(x)[(long long)c * 16 + part];
    float* yp = y + (long long)r * 64 + part * 4;
    atomicAdd(yp + 0, v * xv.x);
    atomicAdd(yp + 1, v * xv.y);
    atomicAdd(yp + 2, v * xv.z);
    atomicAdd(yp + 3, v * xv.w);
}

__global__ __launch_bounds__(THREADS) void spmm_g_items_kernel(
    const int* __restrict__ rows, const int* __restrict__ cols,
    const float* __restrict__ vals, const float* __restrict__ x,
    float* __restrict__ y_items, int nnz, int nU)
{
    long long gid = (long long)blockIdx.x * THREADS + threadIdx.x;
    int e = (int)(gid >> 4);
    if (e >= nnz) return;
    int r = rows[e];
    if (r < nU) return;
    int c = cols[e];
    if (c >= nU) return;
    int part = (int)(gid & 15);
    float v = vals[e];
    float4 xv = reinterpret_cast<const float4*>(x)[(long long)c * 16 + part];
    float* yp = y_items + (long long)(r - nU) * 64 + part * 4;
    atomicAdd(yp + 0, v * xv.x);
    atomicAdd(yp + 1, v * xv.y);
    atomicAdd(yp + 2, v * xv.z);
    atomicAdd(yp + 3, v * xv.w);
}

__global__ __launch_bounds__(THREADS) void combine_kernel(
    const float4* __restrict__ e0, float4* __restrict__ e1,
    const float4* __restrict__ e2, const float4* __restrict__ e3, int n4)
{
    int i = blockIdx.x * THREADS + threadIdx.x;
    if (i >= n4) return;
    float4 a = e0[i], b = e1[i], c = e2[i], d = e3[i];
    e1[i] = make_float4(0.25f * (a.x + b.x + c.x + d.x), 0.25f * (a.y + b.y + c.y + d.y),
                        0.25f * (a.z + b.z + c.z + d.z), 0.25f * (a.w + b.w + c.w + d.w));
}

// ---------------------------------------------------------------------------

extern "C" void kernel_launch(void* const* d_in, const int* in_sizes, int n_in,
                              void* d_out, int out_size, void* d_ws, size_t ws_size,
                              hipStream_t stream) {
    const float* user_emb = (const float*)d_in[0];
    const int*   uu_rows  = (const int*)d_in[1];
    const int*   uu_cols  = (const int*)d_in[2];
    const float* uu_vals  = (const float*)d_in[3];
    const int*   g_rows   = (const int*)d_in[4];
    const int*   g_cols   = (const int*)d_in[5];
    const float* g_vals   = (const float*)d_in[6];
    const int*   users    = (const int*)d_in[7];
    const int*   items    = (const int*)d_in[8];

    const int U    = in_sizes[0] / 64;     // 131072
    const int E_UU = in_sizes[1];          // 4000000
    const int E_G  = in_sizes[4];          // 4000000
    const int B    = in_sizes[7];          // 8192
    const int M    = 32768;                // num_items (fixed per reference)

    const size_t EMB = (size_t)U * 64 * sizeof(float);   // 32 MB
    const size_t MB  = 1024 * 1024;

    char* ws = (char*)d_ws;

    // CSR-path layout (~130 MB):
    float* ACC = (float*)(ws);                      // 0   .. 32M
    float* P0  = (float*)(ws + EMB);                // 32M .. 64M  (g-CSR overlay later)
    float* P1  = (float*)(ws + 2 * EMB);            // 64M .. 96M
    // g overlay (valid after combine; P0/P1 dead then)
    int*  cnt_g = (int*)(ws + EMB);                                  // 32M
    int*  rp_g  = (int*)(ws + EMB + 512 * 1024);                     // 32.5M
    int*  cur_g = (int*)(ws + EMB + 1 * MB);                         // 33M
    int2* se_g  = (int2*)(ws + EMB + MB + 512 * 1024);               // 33.5M .. 65.5M
    float* IT   = (float*)(ws + EMB + 34 * MB);                      // 66M .. 74M
    // uu CSR region
    char* base3 = ws + 3 * EMB;                                      // 96M
    int*  cnt_u = (int*)(base3);                                     // 512K
    int*  cur_u = (int*)(base3 + 512 * 1024);                        // 512K
    int*  partial = (int*)(base3 + 1 * MB);                          // 16K
    int*  rp_u  = (int*)(base3 + 1 * MB + 16 * 1024);                // ~1M
    int2* se_u  = (int2*)(base3 + 2 * MB + 16 * 1024);               // 32 MB
    const size_t needCSR = 3 * EMB + 2 * MB + 16 * 1024 + (size_t)E_UU * 8 + 1024;

    int histGrid = 4096;
    int n4 = U * 16;

    if (ws_size >= needCSR) {
        // ---- build uu CSR ----
        hipMemsetAsync(cnt_u, 0, (size_t)U * 4, stream);
        hist_uu<<<histGrid, THREADS, 0, stream>>>(uu_rows, E_UU, cnt_u);
        scan_block_sums<<<U / 512, THREADS, 0, stream>>>(cnt_u, partial);
        scan_partials<<<1, 64, 0, stream>>>(partial, U / 512, rp_u, U);
        scan_write<<<U / 512, THREADS, 0, stream>>>(cnt_u, partial, rp_u);
        hipMemcpyAsync(cur_u, rp_u, (size_t)U * 4, hipMemcpyDeviceToDevice, stream);
        scatter_uu<<<histGrid, THREADS, 0, stream>>>(uu_rows, uu_cols, uu_vals, E_UU, cur_u, se_u);

        // ---- 3 layers, acc-folded ----
        hipMemsetAsync(ACC, 0, EMB, stream);
        spmm_csr2<<<U / 4, THREADS, 0, stream>>>(rp_u, (const long long*)se_u, user_emb, P0, ACC, U);
        spmm_csr2<<<U / 4, THREADS, 0, stream>>>(rp_u, (const long long*)se_u, P0, P1, ACC, U);
        spmm_csr2<<<U / 4, THREADS, 0, stream>>>(rp_u, (const long long*)se_u, P1, (float*)nullptr, ACC, U);

        // all_users -> ACC
        combine2<<<(n4 + THREADS - 1) / THREADS, THREADS, 0, stream>>>(
            (const float4*)user_emb, (float4*)ACC, n4);

        // ---- build g (item-row) CSR, filtered ----
        hipMemsetAsync(cnt_g, 0, (size_t)M * 4, stream);
        hist_g<<<histGrid, THREADS, 0, stream>>>(g_rows, g_cols, E_G, cnt_g, U);
        scan_block_sums<<<M / 512, THREADS, 0, stream>>>(cnt_g, partial);
        scan_partials<<<1, 64, 0, stream>>>(partial, M / 512, rp_g, M);
        scan_write<<<M / 512, THREADS, 0, stream>>>(cnt_g, partial, rp_g);
        hipMemcpyAsync(cur_g, rp_g, (size_t)M * 4, hipMemcpyDeviceToDevice, stream);
        scatter_g<<<histGrid, THREADS, 0, stream>>>(g_rows, g_cols, g_vals, E_G, cur_g, se_g, U);

        // ---- item propagation + gamma ----
        spmm_csr2<<<M / 4, THREADS, 0, stream>>>(rp_g, (const long long*)se_g, ACC, IT, (float*)nullptr, M);
        final_dot_kernel<<<(B * 16 + THREADS - 1) / THREADS, THREADS, 0, stream>>>(
            ACC, IT, users, items, (float*)d_out, B);
    } else {
        // ---- fallback: atomic path (needs 104 MB) ----
        float* E1 = (float*)ws;
        float* E2 = (float*)(ws + EMB);
        float* E3 = (float*)(ws + 2 * EMB);
        float* IT2 = (float*)(ws + 3 * EMB);
        const size_t itBytes = (size_t)M * 64 * sizeof(float);
        int spmmGrid = (int)(((long long)E_UU * 16 + THREADS - 1) / THREADS);
        int gGrid    = (int)(((long long)E_G * 16 + THREADS - 1) / THREADS);

        hipMemsetAsync(E1, 0, EMB, stream);
        spmm_atomic_kernel<<<spmmGrid, THREADS, 0, stream>>>(uu_rows, uu_cols, uu_vals, user_emb, E1, E_UU);
        hipMemsetAsync(E2, 0, EMB, stream);
        spmm_atomic_kernel<<<spmmGrid, THREADS, 0, stream>>>(uu_rows, uu_cols, uu_vals, E1, E2, E_UU);
        hipMemsetAsync(E3, 0, EMB, stream);
        spmm_atomic_kernel<<<spmmGrid, THREADS, 0, stream>>>(uu_rows, uu_cols, uu_vals, E2, E3, E_UU);
        combine_kernel<<<(n4 + THREADS - 1) / THREADS, THREADS, 0, stream>>>(
            (const float4*)user_emb, (float4*)E1, (const float4*)E2, (const float4*)E3, n4);
        hipMemsetAsync(IT2, 0, itBytes, stream);
        spmm_g_items_kernel<<<gGrid, THREADS, 0, stream>>>(g_rows, g_cols, g_vals, E1, IT2, E_G, U);
        final_dot_kernel<<<(B * 16 + THREADS - 1) / THREADS, THREADS, 0, stream>>>(
            E1, IT2, users, items, (float*)d_out, B);
    }
}

// Round 7
// 657.457 us; speedup vs baseline: 16.2616x; 1.5864x over previous
//
#include <hip/hip_runtime.h>
#include <hip/hip_bf16.h>

#define THREADS 256
#define NB 256        // row buckets for uu CSR build
#define CHUNK 2048    // edges per partition block
#define EPT 8         // CHUNK / THREADS

// ---------------------------------------------------------------------------
// NEW uu-CSR build: bucket hist -> scan -> LDS-staged partition -> per-bucket
// fine sort. All writes coalesced or confined to L2-resident windows.
// ---------------------------------------------------------------------------

__global__ __launch_bounds__(THREADS) void bucket_hist(
    const int* __restrict__ rows, int nnz, int bshift, int* __restrict__ bcnt)
{
    __shared__ int h[NB];
    h[threadIdx.x] = 0;
    __syncthreads();
    long long stride = (long long)gridDim.x * THREADS;
    for (long long e = (long long)blockIdx.x * THREADS + threadIdx.x; e < nnz; e += stride)
        atomicAdd(&h[rows[e] >> bshift], 1);
    __syncthreads();
    int v = h[threadIdx.x];
    if (v) atomicAdd(&bcnt[threadIdx.x], v);
}

// 1-thread scan of NB bucket counts; also seeds gcur and writes rp[U]=E.
__global__ void scan_buckets(const int* __restrict__ bcnt, int* __restrict__ bbase,
                             int* __restrict__ gcur, int* __restrict__ rp, int U_, int E_)
{
    if (threadIdx.x == 0 && blockIdx.x == 0) {
        int run = 0;
        for (int i = 0; i < NB; i++) { bbase[i] = run; gcur[i] = run; run += bcnt[i]; }
        bbase[NB] = run;
        rp[U_] = E_;
    }
}

// Block-synchronous multisplit: stage CHUNK edges in bucket order in LDS,
// reserve per-bucket global space once per chunk, copy out coalesced.
// mid payload: [63:32]=val bits, [28:20]=row&(RPB-1), [19:0]=col
__global__ __launch_bounds__(THREADS) void partition_uu(
    const int* __restrict__ rows, const int* __restrict__ cols,
    const float* __restrict__ vals, int nnz, int bshift,
    unsigned long long* __restrict__ mid, int* __restrict__ gcur)
{
    __shared__ int hist[NB], lbase[NB], lcur[NB], gbase[NB];
    __shared__ unsigned long long stage[CHUNK];
    __shared__ int dst[CHUNK];
    int t = threadIdx.x;
    long long cb = (long long)blockIdx.x * CHUNK;
    hist[t] = 0; lcur[t] = 0;
    __syncthreads();

    int rl[EPT], cl[EPT], vb[EPT];
    #pragma unroll
    for (int j = 0; j < EPT; j++) {
        long long e = cb + j * THREADS + t;
        if (e < nnz) {
            rl[j] = rows[e]; cl[j] = cols[e]; vb[j] = __float_as_int(vals[e]);
            atomicAdd(&hist[rl[j] >> bshift], 1);
        } else rl[j] = -1;
    }
    __syncthreads();

    int v = hist[t];
    lbase[t] = v;
    __syncthreads();
    for (int off = 1; off < NB; off <<= 1) {
        int add = (t >= off) ? lbase[t - off] : 0;
        __syncthreads();
        lbase[t] += add;
        __syncthreads();
    }
    int excl = lbase[t] - v;
    int gb = 0;
    if (v) gb = atomicAdd(&gcur[t], v);
    gbase[t] = gb;
    lbase[t] = excl;            // own slot only; published by next barrier
    __syncthreads();

    #pragma unroll
    for (int j = 0; j < EPT; j++) {
        if (rl[j] >= 0) {
            int b = rl[j] >> bshift;
            int rank = atomicAdd(&lcur[b], 1);
            int pos = lbase[b] + rank;
            stage[pos] = ((unsigned long long)(unsigned)vb[j] << 32)
                       | ((unsigned)(rl[j] & ((1 << bshift) - 1)) << 20)
                       | (unsigned)cl[j];
            dst[pos] = gbase[b] + rank;
        }
    }
    __syncthreads();
    int total = lbase[NB - 1] + hist[NB - 1];
    for (int i = t; i < total; i += THREADS)
        mid[dst[i]] = stage[i];
}

// One block per bucket: per-row count -> in-block scan -> rp write +
// scatter confined to the bucket's (L2-resident) window. RPB must be 512.
__global__ __launch_bounds__(THREADS) void fine_uu(
    const unsigned long long* __restrict__ mid, const int* __restrict__ bbase,
    int2* __restrict__ se, int* __restrict__ rp, int bshift)
{
    __shared__ int rcnt[512];
    __shared__ int sc[THREADS];
    int b = blockIdx.x, t = threadIdx.x;
    int s = bbase[b], e = bbase[b + 1];
    int rmask = (1 << bshift) - 1;      // 511
    rcnt[t] = 0; rcnt[t + 256] = 0;
    __syncthreads();
    for (int i = s + t; i < e; i += THREADS)
        atomicAdd(&rcnt[(int)(mid[i] >> 20) & rmask], 1);
    __syncthreads();
    int a0 = rcnt[2 * t], a1 = rcnt[2 * t + 1];
    int psum = a0 + a1;
    sc[t] = psum;
    __syncthreads();
    for (int off = 1; off < THREADS; off <<= 1) {
        int add = (t >= off) ? sc[t - off] : 0;
        __syncthreads();
        sc[t] += add;
        __syncthreads();
    }
    int pexcl = sc[t] - psum;
    int rowg = (b << bshift) + 2 * t;
    rp[rowg]     = s + pexcl;
    rp[rowg + 1] = s + pexcl + a0;
    rcnt[2 * t] = pexcl;
    rcnt[2 * t + 1] = pexcl + a0;
    __syncthreads();
    for (int i = s + t; i < e; i += THREADS) {
        unsigned long long w = mid[i];
        int rloc = (int)(w >> 20) & rmask;
        int pos = s + atomicAdd(&rcnt[rloc], 1);
        se[pos] = make_int2((int)(w & 0xFFFFF), (int)(w >> 32));
    }
}

// ---------------------------------------------------------------------------
// OLD-style build kept for the (filtered) g graph: hist -> scan -> scatter
// ---------------------------------------------------------------------------

__global__ __launch_bounds__(THREADS) void hist_g(
    const int* __restrict__ rows, const int* __restrict__ cols,
    int nnz, int* __restrict__ cnt, int nU)
{
    int stride = gridDim.x * THREADS;
    for (int e = blockIdx.x * THREADS + threadIdx.x; e < nnz; e += stride) {
        int r = rows[e];
        if (r >= nU && cols[e] < nU) atomicAdd(&cnt[r - nU], 1);
    }
}

__global__ __launch_bounds__(THREADS) void scan_block_sums(
    const int* __restrict__ cnt, int* __restrict__ partial)
{
    __shared__ int lds[THREADS];
    int i = blockIdx.x * 512 + threadIdx.x * 2;
    lds[threadIdx.x] = cnt[i] + cnt[i + 1];
    __syncthreads();
    for (int off = 128; off > 0; off >>= 1) {
        if (threadIdx.x < off) lds[threadIdx.x] += lds[threadIdx.x + off];
        __syncthreads();
    }
    if (threadIdx.x == 0) partial[blockIdx.x] = lds[0];
}

__global__ void scan_partials(int* partial, int nb, int* rp, int n)
{
    if (threadIdx.x == 0 && blockIdx.x == 0) {
        int run = 0;
        for (int i = 0; i < nb; i++) { int v = partial[i]; partial[i] = run; run += v; }
        rp[n] = run;
    }
}

__global__ __launch_bounds__(THREADS) void scan_write(
    const int* __restrict__ cnt, const int* __restrict__ partial, int* __restrict__ rp)
{
    __shared__ int lds[THREADS];
    int t = threadIdx.x;
    int i = blockIdx.x * 512 + t * 2;
    int a0 = cnt[i], a1 = cnt[i + 1];
    int s = a0 + a1;
    lds[t] = s;
    __syncthreads();
    for (int off = 1; off < THREADS; off <<= 1) {
        int v = (t >= off) ? lds[t - off] : 0;
        __syncthreads();
        lds[t] += v;
        __syncthreads();
    }
    int excl = lds[t] - s;
    int base = partial[blockIdx.x];
    rp[i] = base + excl;
    rp[i + 1] = base + excl + a0;
}

__global__ __launch_bounds__(THREADS) void scatter_g(
    const int* __restrict__ rows, const int* __restrict__ cols,
    const float* __restrict__ vals, int nnz, int* __restrict__ cur,
    int2* __restrict__ se, int nU)
{
    int stride = gridDim.x * THREADS;
    for (int e = blockIdx.x * THREADS + threadIdx.x; e < nnz; e += stride) {
        int r = rows[e];
        if (r >= nU) {
            int c = cols[e];
            if (c < nU) {
                int p = atomicAdd(&cur[r - nU], 1);
                se[p] = make_int2(c, __float_as_int(vals[e]));
            }
        }
    }
}

// ---------------------------------------------------------------------------
// Gather SpMM: one wave per row, lane = feature. Cooperative edge fetch,
// readlane broadcast -> scalar-base gathers, 8 independent in-flight gathers.
// mode: 0 = y only, 1 = acc store, 2 = acc add, 3 = acc = 0.25*(ue+acc+a)
// ---------------------------------------------------------------------------
__global__ __launch_bounds__(THREADS) void spmm_csr2(
    const int* __restrict__ rp, const long long* __restrict__ se,
    const float* __restrict__ x, float* __restrict__ y,
    float* __restrict__ acc, const float* __restrict__ ue,
    int mode, int nrows)
{
    int w = (blockIdx.x * THREADS + threadIdx.x) >> 6;
    int lane = threadIdx.x & 63;
    if (w >= nrows) return;
    int s = rp[w], e = rp[w + 1];

    float a0 = 0.f, a1 = 0.f, a2 = 0.f, a3 = 0.f;
    float a4 = 0.f, a5 = 0.f, a6 = 0.f, a7 = 0.f;

    for (int base = s; base < e; base += 64) {
        int avail = e - base;
        long long packed = 0;
        if (lane < avail)
            packed = __builtin_nontemporal_load(se + base + lane);
        int evc = (int)(packed & 0xffffffffLL);
        int evv = (int)(packed >> 32);
        int n = avail < 64 ? avail : 64;
        int nIter = (n + 7) & ~7;
        for (int i = 0; i < nIter; i += 8) {
            int   c0 = __builtin_amdgcn_readlane(evc, i + 0);
            float v0 = __int_as_float(__builtin_amdgcn_readlane(evv, i + 0));
            int   c1 = __builtin_amdgcn_readlane(evc, i + 1);
            float v1 = __int_as_float(__builtin_amdgcn_readlane(evv, i + 1));
            int   c2 = __builtin_amdgcn_readlane(evc, i + 2);
            float v2 = __int_as_float(__builtin_amdgcn_readlane(evv, i + 2));
            int   c3 = __builtin_amdgcn_readlane(evc, i + 3);
            float v3 = __int_as_float(__builtin_amdgcn_readlane(evv, i + 3));
            int   c4 = __builtin_amdgcn_readlane(evc, i + 4);
            float v4 = __int_as_float(__builtin_amdgcn_readlane(evv, i + 4));
            int   c5 = __builtin_amdgcn_readlane(evc, i + 5);
            float v5 = __int_as_float(__builtin_amdgcn_readlane(evv, i + 5));
            int   c6 = __builtin_amdgcn_readlane(evc, i + 6);
            float v6 = __int_as_float(__builtin_amdgcn_readlane(evv, i + 6));
            int   c7 = __builtin_amdgcn_readlane(evc, i + 7);
            float v7 = __int_as_float(__builtin_amdgcn_readlane(evv, i + 7));
            float g0 = x[((long long)c0 << 6) + lane];
            float g1 = x[((long long)c1 << 6) + lane];
            float g2 = x[((long long)c2 << 6) + lane];
            float g3 = x[((long long)c3 << 6) + lane];
            float g4 = x[((long long)c4 << 6) + lane];
            float g5 = x[((long long)c5 << 6) + lane];
            float g6 = x[((long long)c6 << 6) + lane];
            float g7 = x[((long long)c7 << 6) + lane];
            a0 += v0 * g0; a1 += v1 * g1; a2 += v2 * g2; a3 += v3 * g3;
            a4 += v4 * g4; a5 += v5 * g5; a6 += v6 * g6; a7 += v7 * g7;
        }
    }
    float a = ((a0 + a1) + (a2 + a3)) + ((a4 + a5) + (a6 + a7));
    long long oi = ((long long)w << 6) + lane;
    if (y) __builtin_nontemporal_store(a, y + oi);
    if (mode == 1)      acc[oi] = a;
    else if (mode == 2) acc[oi] += a;
    else if (mode == 3) acc[oi] = 0.25f * (ue[oi] + acc[oi] + a);
}

__global__ __launch_bounds__(THREADS) void final_dot_kernel(
    const float* __restrict__ au, const float* __restrict__ it,
    const int* __restrict__ users, const int* __restrict__ items,
    float* __restrict__ out, int B)
{
    int gid = blockIdx.x * THREADS + threadIdx.x;
    int b = gid >> 4;
    if (b >= B) return;
    int part = gid & 15;
    float4 uv = reinterpret_cast<const float4*>(au)[(long long)users[b] * 16 + part];
    float4 iv = reinterpret_cast<const float4*>(it)[(long long)items[b] * 16 + part];
    float s = uv.x * iv.x + uv.y * iv.y + uv.z * iv.z + uv.w * iv.w;
    s += __shfl_xor(s, 1);
    s += __shfl_xor(s, 2);
    s += __shfl_xor(s, 4);
    s += __shfl_xor(s, 8);
    if (part == 0) out[b] = s;
}

// ---------------------------------------------------------------------------
// Fallback (atomic path) in case ws/shape assumptions fail
// ---------------------------------------------------------------------------
__global__ __launch_bounds__(THREADS) void spmm_atomic_kernel(
    const int* __restrict__ rows, const int* __restrict__ cols,
    const float* __restrict__ vals, const float* __restrict__ x,
    float* __restrict__ y, int nnz)
{
    long long gid = (long long)blockIdx.x * THREADS + threadIdx.x;
    int e = (int)(gid >> 4);
    if (e >= nnz) return;
    int part = (int)(gid & 15);
    int r = rows[e];
    int c = cols[e];
    float v = vals[e];
    float4 xv = reinterpret_cast<const float4*>(x)[(long long)c * 16 + part];
    float* yp = y + (long long)r * 64 + part * 4;
    atomicAdd(yp + 0, v * xv.x);
    atomicAdd(yp + 1, v * xv.y);
    atomicAdd(yp + 2, v * xv.z);
    atomicAdd(yp + 3, v * xv.w);
}

__global__ __launch_bounds__(THREADS) void spmm_g_items_kernel(
    const int* __restrict__ rows, const int* __restrict__ cols,
    const float* __restrict__ vals, const float* __restrict__ x,
    float* __restrict__ y_items, int nnz, int nU)
{
    long long gid = (long long)blockIdx.x * THREADS + threadIdx.x;
    int e = (int)(gid >> 4);
    if (e >= nnz) return;
    int r = rows[e];
    if (r < nU) return;
    int c = cols[e];
    if (c >= nU) return;
    int part = (int)(gid & 15);
    float v = vals[e];
    float4 xv = reinterpret_cast<const float4*>(x)[(long long)c * 16 + part];
    float* yp = y_items + (long long)(r - nU) * 64 + part * 4;
    atomicAdd(yp + 0, v * xv.x);
    atomicAdd(yp + 1, v * xv.y);
    atomicAdd(yp + 2, v * xv.z);
    atomicAdd(yp + 3, v * xv.w);
}

__global__ __launch_bounds__(THREADS) void combine_kernel(
    const float4* __restrict__ e0, float4* __restrict__ e1,
    const float4* __restrict__ e2, const float4* __restrict__ e3, int n4)
{
    int i = blockIdx.x * THREADS + threadIdx.x;
    if (i >= n4) return;
    float4 a = e0[i], b = e1[i], c = e2[i], d = e3[i];
    e1[i] = make_float4(0.25f * (a.x + b.x + c.x + d.x), 0.25f * (a.y + b.y + c.y + d.y),
                        0.25f * (a.z + b.z + c.z + d.z), 0.25f * (a.w + b.w + c.w + d.w));
}

// ---------------------------------------------------------------------------

extern "C" void kernel_launch(void* const* d_in, const int* in_sizes, int n_in,
                              void* d_out, int out_size, void* d_ws, size_t ws_size,
                              hipStream_t stream) {
    const float* user_emb = (const float*)d_in[0];
    const int*   uu_rows  = (const int*)d_in[1];
    const int*   uu_cols  = (const int*)d_in[2];
    const float* uu_vals  = (const float*)d_in[3];
    const int*   g_rows   = (const int*)d_in[4];
    const int*   g_cols   = (const int*)d_in[5];
    const float* g_vals   = (const float*)d_in[6];
    const int*   users    = (const int*)d_in[7];
    const int*   items    = (const int*)d_in[8];

    const int U    = in_sizes[0] / 64;     // 131072
    const int E_UU = in_sizes[1];          // 4000000
    const int E_G  = in_sizes[4];          // 4000000
    const int B    = in_sizes[7];          // 8192
    const int M    = 32768;                // num_items (fixed per reference)

    const size_t EMB = (size_t)U * 64 * sizeof(float);   // 32 MB
    const size_t MB  = 1024 * 1024;

    char* ws = (char*)d_ws;

    // Layout (~130 MB):
    float* ACC = (float*)(ws);                      // 0..32M (also `mid` during build)
    float* P0  = (float*)(ws + EMB);                // 32..64M (g overlay later)
    float* P1  = (float*)(ws + 2 * EMB);            // 64..96M
    unsigned long long* mid = (unsigned long long*)(ws);   // aliases ACC (dead then)
    // g overlay (valid after layer spmms; P0/P1 dead then)
    int*  cnt_g = (int*)(ws + EMB);
    int*  rp_g  = (int*)(ws + EMB + 512 * 1024);
    int*  cur_g = (int*)(ws + EMB + 1 * MB);
    int2* se_g  = (int2*)(ws + EMB + MB + 512 * 1024);
    float* IT   = (float*)(ws + EMB + 34 * MB);
    // uu build region
    char* base3 = ws + 3 * EMB;                     // 96M
    int*  bcnt    = (int*)(base3);                  // NB ints
    int*  gcur    = (int*)(base3 + 4096);           // NB ints
    int*  bbase   = (int*)(base3 + 8192);           // NB+1 ints
    int*  partial = (int*)(base3 + 1 * MB);         // g scan partials
    int*  rp_u  = (int*)(base3 + 1 * MB + 16 * 1024);
    int2* se_u  = (int2*)(base3 + 2 * MB + 16 * 1024);
    const size_t needCSR = 3 * EMB + 2 * MB + 16 * 1024 + (size_t)E_UU * 8 + 1024;

    int n4 = U * 16;

    bool newPath = (ws_size >= needCSR) && (U == 131072) &&
                   ((size_t)E_UU * 8 <= EMB) && (E_UU > 0);

    if (newPath) {
        const int bshift = 9;                       // U/NB = 512 rows per bucket
        // ---- build uu CSR (bucket sort) ----
        hipMemsetAsync(bcnt, 0, NB * 4, stream);
        bucket_hist<<<1024, THREADS, 0, stream>>>(uu_rows, E_UU, bshift, bcnt);
        scan_buckets<<<1, 64, 0, stream>>>(bcnt, bbase, gcur, rp_u, U, E_UU);
        int nChunks = (E_UU + CHUNK - 1) / CHUNK;
        partition_uu<<<nChunks, THREADS, 0, stream>>>(uu_rows, uu_cols, uu_vals,
                                                      E_UU, bshift, mid, gcur);
        fine_uu<<<NB, THREADS, 0, stream>>>(mid, bbase, se_u, rp_u, bshift);

        // ---- 3 layers; ACC store/add/finalize folded into spmm ----
        spmm_csr2<<<U / 4, THREADS, 0, stream>>>(rp_u, (const long long*)se_u,
            user_emb, P0, ACC, (const float*)nullptr, 1, U);
        spmm_csr2<<<U / 4, THREADS, 0, stream>>>(rp_u, (const long long*)se_u,
            P0, P1, ACC, (const float*)nullptr, 2, U);
        spmm_csr2<<<U / 4, THREADS, 0, stream>>>(rp_u, (const long long*)se_u,
            P1, (float*)nullptr, ACC, user_emb, 3, U);

        // ---- build g (item-row) CSR, filtered (old path) ----
        hipMemsetAsync(cnt_g, 0, (size_t)M * 4, stream);
        hist_g<<<4096, THREADS, 0, stream>>>(g_rows, g_cols, E_G, cnt_g, U);
        scan_block_sums<<<M / 512, THREADS, 0, stream>>>(cnt_g, partial);
        scan_partials<<<1, 64, 0, stream>>>(partial, M / 512, rp_g, M);
        scan_write<<<M / 512, THREADS, 0, stream>>>(cnt_g, partial, rp_g);
        hipMemcpyAsync(cur_g, rp_g, (size_t)M * 4, hipMemcpyDeviceToDevice, stream);
        scatter_g<<<4096, THREADS, 0, stream>>>(g_rows, g_cols, g_vals, E_G, cur_g, se_g, U);

        // ---- item propagation + gamma ----
        spmm_csr2<<<M / 4, THREADS, 0, stream>>>(rp_g, (const long long*)se_g,
            ACC, IT, (float*)nullptr, (const float*)nullptr, 0, M);
        final_dot_kernel<<<(B * 16 + THREADS - 1) / THREADS, THREADS, 0, stream>>>(
            ACC, IT, users, items, (float*)d_out, B);
    } else {
        // ---- fallback: atomic path (needs 104 MB) ----
        float* E1 = (float*)ws;
        float* E2 = (float*)(ws + EMB);
        float* E3 = (float*)(ws + 2 * EMB);
        float* IT2 = (float*)(ws + 3 * EMB);
        const size_t itBytes = (size_t)M * 64 * sizeof(float);
        int spmmGrid = (int)(((long long)E_UU * 16 + THREADS - 1) / THREADS);
        int gGrid    = (int)(((long long)E_G * 16 + THREADS - 1) / THREADS);

        hipMemsetAsync(E1, 0, EMB, stream);
        spmm_atomic_kernel<<<spmmGrid, THREADS, 0, stream>>>(uu_rows, uu_cols, uu_vals, user_emb, E1, E_UU);
        hipMemsetAsync(E2, 0, EMB, stream);
        spmm_atomic_kernel<<<spmmGrid, THREADS, 0, stream>>>(uu_rows, uu_cols, uu_vals, E1, E2, E_UU);
        hipMemsetAsync(E3, 0, EMB, stream);
        spmm_atomic_kernel<<<spmmGrid, THREADS, 0, stream>>>(uu_rows, uu_cols, uu_vals, E2, E3, E_UU);
        combine_kernel<<<(n4 + THREADS - 1) / THREADS, THREADS, 0, stream>>>(
            (const float4*)user_emb, (float4*)E1, (const float4*)E2, (const float4*)E3, n4);
        hipMemsetAsync(IT2, 0, itBytes, stream);
        spmm_g_items_kernel<<<gGrid, THREADS, 0, stream>>>(g_rows, g_cols, g_vals, E1, IT2, E_G, U);
        final_dot_kernel<<<(B * 16 + THREADS - 1) / THREADS, THREADS, 0, stream>>>(
            E1, IT2, users, items, (float*)d_out, B);
    }
}